// Round 16
// baseline (862.972 us; speedup 1.0000x reference)
//
#include <hip/hip_runtime.h>

#define PB 22
#define HB 64
#define EB 462
#define NL 5

// ws (shorts): hi tables then lo mirror at +WTOT
#define W1T_OFF  0        // [5][64][128]
#define W2T_OFF  40960    // [5][64][64]
#define WC1T_OFF 61440    // [5][64][64]  K sigma-permuted
#define WN1T_OFF 81920    // [5][64][128]
#define WN2T_OFF 122880   // [5][64][64]
#define WTOT     143360

typedef __attribute__((ext_vector_type(8))) short short8v;
typedef __attribute__((ext_vector_type(4))) float f32x4;
typedef __attribute__((ext_vector_type(4))) unsigned uint4v;
typedef __attribute__((ext_vector_type(2))) unsigned uint2v;

#define MFMA16(a,b,c) __builtin_amdgcn_mfma_f32_16x16x32_bf16((a),(b),(c),0,0,0)

__device__ __forceinline__ short tobf(float f){
  unsigned u = __float_as_uint(f);
  return (short)((u + 0x7FFFu + ((u>>16)&1u)) >> 16);
}
__device__ __forceinline__ float bf2f(short h){
  return __uint_as_float(((unsigned)(unsigned short)h) << 16);
}
__device__ __forceinline__ void split2(float v, short &hi, short &lo){
  hi = tobf(v);
  lo = tobf(v - bf2f(hi));
}
__device__ __forceinline__ void splitT(float v, short &hi, short &lo){
  unsigned u = __float_as_uint(v);
  hi = (short)(u >> 16);
  float lf = v - __uint_as_float(u & 0xFFFF0000u);
  lo = (short)(__float_as_uint(lf) >> 16);
}
__device__ __forceinline__ float trunc_res(float v){
  return v - __uint_as_float(__float_as_uint(v) & 0xFFFF0000u);
}
__device__ __forceinline__ unsigned pack_hi(float a, float b){
  return __builtin_amdgcn_perm(__float_as_uint(b), __float_as_uint(a), 0x07060302u);
}
// pack two f32 -> u32 of two RNE bf16 (a in low short)
__device__ __forceinline__ unsigned rne_pack(float a, float b){
  unsigned ua = __float_as_uint(a);
  unsigned ub = __float_as_uint(b);
  ua = (ua + 0x7FFFu + ((ua>>16)&1u)) >> 16;
  ub = (ub + 0x7FFFu + ((ub>>16)&1u)) & 0xFFFF0000u;
  return ua | ub;
}
__device__ __forceinline__ float siluf(float x){
  return x * __builtin_amdgcn_rcpf(1.f + __expf(-x));
}
__device__ __forceinline__ float sigf(float x){
  return __builtin_amdgcn_rcpf(1.f + __expf(-x));
}
__device__ __forceinline__ float tanhff(float x){
  return fmaf(-2.f, __builtin_amdgcn_rcpf(__expf(2.f*x) + 1.f), 1.f);
}
__device__ __forceinline__ float xorsum_q(float x){
  x += __shfl_xor(x, 16);
  x += __shfl_xor(x, 32);
  return x;
}

__global__ void prep_weights(const float* __restrict__ We1, const float* __restrict__ We2,
                             const float* __restrict__ Wc1, const float* __restrict__ Wn1,
                             const float* __restrict__ Wn2, short* __restrict__ ws){
  int i = blockIdx.x*256 + threadIdx.x;
  if (i >= WTOT) return;
  float v;
  if (i < W2T_OFF){            int l=i>>13, r=i&8191, n=r>>7, k=r&127; v = We1[(l*130+k)*64+n]; }
  else if (i < WC1T_OFF){ int j=i-W2T_OFF;  int l=j>>12, r=j&4095, n=r>>6, k=r&63; v = We2[(l*64+k)*64+n]; }
  else if (i < WN1T_OFF){ int j=i-WC1T_OFF; int l=j>>12, r=j&4095, n=r>>6, k=r&63;
    int kk = (k>>5)*32 + ((k>>2)&1)*16 + ((k>>3)&3)*4 + (k&3);
    v = Wc1[(l*64+kk)*64+n]; }
  else if (i < WN2T_OFF){ int j=i-WN1T_OFF; int l=j>>13, r=j&8191, n=r>>7, k=r&127; v = Wn1[(l*128+k)*64+n]; }
  else {                  int j=i-WN2T_OFF; int l=j>>12, r=j&4095, n=r>>6, k=r&63; v = Wn2[(l*64+k)*64+n]; }
  short hi, lo;
  split2(v, hi, lo);
  ws[i] = hi; ws[WTOT+i] = lo;
}

// ---- LDS pool byte offsets (16B aligned) ----
// 512-thread blocks (8 waves). SAF aliases WL2 (phase-disjoint).
// M: 128 rows x 72 shorts (cols 0-63 bf16 messages, 64-69 td f32).
// smean lives in sdx4[88..90].
#define O_Y1   0        // float[22*68]; aliased UHI short[22*72] in C/D
#define O_Y2   5984     // float[22*68]; aliased ULO
#define O_SHBH 11968    // short[22*72]
#define O_SHBL 15136    // short[22*72]
#define O_WL2  18304    // short[64*72]  W2-lo; aliased SAF float[22*68]
#define O_WC1  27520    // short[64*72]  Wc1-hi
#define O_M    36736    // short[128*72] chunk messages + td
#define O_SCAL 55168    // float[256]: BE2@0 BC1@64 WA@128 WC2@192
#define O_SXC  56192    // float[23*4]
#define O_SX0  56560
#define O_SDX  56928    // float[92]; [88..90] = smean (epilogue only)
#define O_SER  57296    // uchar[512]
#define O_SEC  57808
#define POOLSZ 58320    // 56.95 KiB; 2 blocks/CU = 16 waves

__global__ __launch_bounds__(512, 2)
void egnn13(const float* __restrict__ gt,  const float* __restrict__ gx,
            const float* __restrict__ gh0, const float* __restrict__ embW,
            const float* __restrict__ embB,
            const float* __restrict__ We1, const float* __restrict__ be1,
            const float* __restrict__ be2, const float* __restrict__ Wa,
            const float* __restrict__ ba,  const float* __restrict__ bc1,
            const float* __restrict__ Wc2, const float* __restrict__ bn1,
            const float* __restrict__ bn2,
            const int* __restrict__ rows,  const int* __restrict__ cols,
            const short* __restrict__ wbt, float* __restrict__ out)
{
  const int b    = blockIdx.x;
  const int tid  = threadIdx.x;
  const int lane = tid & 63;
  const int wv   = tid >> 6;        // 0..7
  const int c    = lane & 15;
  const int q    = lane >> 4;
  const int Mt   = wv >> 2;         // phases C/D: node tile
  const int nb   = wv & 3;          // phases C/D: feature block

  __shared__ __align__(16) char pool[POOLSZ];
  float* Y1s   = (float*)(pool + O_Y1);
  float* Y2s   = (float*)(pool + O_Y2);
  short* SHBH  = (short*)(pool + O_SHBH);
  short* SHBL  = (short*)(pool + O_SHBL);
  short* WL2   = (short*)(pool + O_WL2);
  float* SAF   = (float*)(pool + O_WL2);   // alias (see layout note)
  short* WC1H  = (short*)(pool + O_WC1);
  short* Mb    = (short*)(pool + O_M);
  float* SCALf = (float*)(pool + O_SCAL);
  float* sxc4  = (float*)(pool + O_SXC);
  float* sx04  = (float*)(pool + O_SX0);
  float* sdx4  = (float*)(pool + O_SDX);
  unsigned char* SER = (unsigned char*)(pool + O_SER);
  unsigned char* SEC = (unsigned char*)(pool + O_SEC);
  short* UHI = (short*)(pool + O_Y1);
  short* ULO = (short*)(pool + O_Y2);

  // gather tasks: one per thread.
  // tid < 352: fq-task (n = tid>>4, fq = tid&15)
  // tid in [352,418): td-task (n = u/3, k = u%3)
  const int nA  = tid >> 4;
  const int fqA = tid & 15;
  const bool hasA  = (tid < 352);
  const bool hasTD = (tid >= 352 && tid < 418);
  const int tdn = (tid - 352) / 3, tdk = (tid - 352) % 3;

  const float tb = gt[b];

  for (int i = tid; i < 92; i += 512){
    int node = i >> 2, k = i & 3;
    float v = (k < 3 && node < PB) ? gx[b*66 + node*3 + k] : 0.f;
    sx04[i] = v; sxc4[i] = v;
  }
  // permuted edge order: slot k (<462) = node (k%22)'s (k/22)-th incoming edge;
  // slots 462..511 -> node 21 (never gathered: gather slots n+22j <= 461).
  for (int k = tid; k < 512; k += 512){
    int r = 21, c2 = 21;
    if (k < EB){
      int n = k % 22, s = k / 22;
      int e;
      if (s < n) e = 2*(21*s - (s*(s-1))/2 + (n - s - 1)) + 1;
      else       e = 2*(21*n - (n*(n-1))/2 + (s - n));
      r  = rows[b*EB+e] - b*PB;
      c2 = cols[b*EB+e] - b*PB;
    }
    SER[k] = (unsigned char)r; SEC[k] = (unsigned char)c2;
  }
  for (int i = tid; i < PB*HB; i += 512){
    int n = i >> 6, j = i & 63;
    float acc = embB[j] + tb*embW[PB*HB + j];
    #pragma unroll
    for (int k = 0; k < PB; k++) acc = fmaf(gh0[n*PB+k], embW[k*HB+j], acc);
    short hi, lo; splitT(acc, hi, lo);
    SHBH[n*72+j] = hi; SHBL[n*72+j] = lo;
  }
  __syncthreads();

  #pragma unroll 1
  for (int l = 0; l < NL; l++){
    // ---------- phase A ----------
    if (tid < 92) sdx4[tid] = 0.f;
    if (tid < 64){
      SCALf[      tid] = be2[l*64+tid];
      SCALf[ 64 + tid] = bc1[l*64+tid];
      SCALf[128 + tid] = Wa [l*64+tid];
      SCALf[192 + tid] = Wc2[l*64+tid];
    }
    { const short* g2lo = wbt + WTOT + W2T_OFF + l*4096;
      const short* g1hi = wbt + WC1T_OFF + l*4096;
      for (int i = tid; i < 512; i += 512){
        int col = i>>3, kc = i&7;
        *(short8v*)(WL2  + col*72 + kc*8) = *(const short8v*)(g2lo + col*64 + kc*8);
        *(short8v*)(WC1H + col*72 + kc*8) = *(const short8v*)(g1hi + col*64 + kc*8);
      } }
    // node GEMM Y1/Y2 (16 tasks over 8 waves)
    #pragma unroll 1
    for (int task = wv; task < 16; task += 8){
      const int Yv = task>>3, Mtt = (task>>2)&1, nt = task&3;
      const int arow = Mtt*16 + c, arowR = arow < PB ? arow : PB-1;
      const short* bp = wbt + W1T_OFF + (l*64 + nt*16 + c)*128 + Yv*64;
      const float initv = Yv ? 0.f : be1[l*64 + nt*16 + c];
      f32x4 acc = {initv, initv, initv, initv};
      #pragma unroll
      for (int kt = 0; kt < 2; kt++){
        short8v ah = *(const short8v*)(SHBH + arowR*72 + kt*32 + q*8);
        short8v al = *(const short8v*)(SHBL + arowR*72 + kt*32 + q*8);
        short8v bh = *(const short8v*)(bp + kt*32 + q*8);
        short8v bl = *(const short8v*)(bp + WTOT + kt*32 + q*8);
        acc = MFMA16(ah, bh, acc);
        acc = MFMA16(al, bh, acc);
        acc = MFMA16(ah, bl, acc);
      }
      float* Yp = Yv ? Y2s : Y1s;
      #pragma unroll
      for (int r = 0; r < 4; r++){
        int row = Mtt*16 + q*4 + r;
        if (row < PB) Yp[row*68 + nt*16 + c] = acc[r];
      }
    }
    short8v W2h[2][4];
    #pragma unroll
    for (int nt = 0; nt < 4; nt++)
      #pragma unroll
      for (int kt = 0; kt < 2; kt++)
        W2h[kt][nt] = *(const short8v*)(wbt + W2T_OFF + (l*64+nt*16+c)*64 + kt*32 + q*8);
    f32x4 w8a[2], w8b[2], w9a[2], w9b[2];
    #pragma unroll
    for (int kt = 0; kt < 2; kt++){
      const float* p8 = We1 + (l*130+128)*64 + kt*32 + q*8;
      w8a[kt] = *(const f32x4*)p8;        w8b[kt] = *(const f32x4*)(p8+4);
      w9a[kt] = *(const f32x4*)(p8+64);   w9b[kt] = *(const f32x4*)(p8+68);
    }
    const float bav = ba[l];
    __syncthreads();   // b1

    // ---------- phase B: 4 chunks x 8 tiles; non-atomic M + register gather ----------
    f32x4 gA = {0.f,0.f,0.f,0.f};
    float tdacc = 0.f;
    #pragma unroll 1
    for (int ch = 0; ch < 4; ch++){
      {
        const int e = (ch*8 + wv)*16 + c;
        const int sl = wv*16 + c;             // local slot in chunk buffer [0,128)
        const int nr = SER[e], nc = SEC[e];
        const f32x4 xr = *(const f32x4*)(sxc4 + nr*4);
        const f32x4 xn = *(const f32x4*)(sxc4 + nc*4);
        const float d0 = xr[0]-xn[0], d1 = xr[1]-xn[1], d2 = xr[2]-xn[2];
        const float rad = d0*d0 + d1*d1 + d2*d2;
        const f32x4 zr = *(const f32x4*)(sx04 + nr*4);
        const f32x4 zn = *(const f32x4*)(sx04 + nc*4);
        const float g0 = zr[0]-zn[0], g1 = zr[1]-zn[1], g2 = zr[2]-zn[2];
        const float ea = g0*g0 + g1*g1 + g2*g2;
        short8v m1h[2], m1l[2];
        #pragma unroll
        for (int kt = 0; kt < 2; kt++){
          const f32x4 ya = *(const f32x4*)(Y1s + nr*68 + kt*32 + q*8);
          const f32x4 yb = *(const f32x4*)(Y1s + nr*68 + kt*32 + q*8 + 4);
          const f32x4 za = *(const f32x4*)(Y2s + nc*68 + kt*32 + q*8);
          const f32x4 zb = *(const f32x4*)(Y2s + nc*68 + kt*32 + q*8 + 4);
          float s0 = siluf(fmaf(rad, w8a[kt][0], fmaf(ea, w9a[kt][0], ya[0]+za[0])));
          float s1 = siluf(fmaf(rad, w8a[kt][1], fmaf(ea, w9a[kt][1], ya[1]+za[1])));
          float s2 = siluf(fmaf(rad, w8a[kt][2], fmaf(ea, w9a[kt][2], ya[2]+za[2])));
          float s3 = siluf(fmaf(rad, w8a[kt][3], fmaf(ea, w9a[kt][3], ya[3]+za[3])));
          float s4 = siluf(fmaf(rad, w8b[kt][0], fmaf(ea, w9b[kt][0], yb[0]+zb[0])));
          float s5 = siluf(fmaf(rad, w8b[kt][1], fmaf(ea, w9b[kt][1], yb[1]+zb[1])));
          float s6 = siluf(fmaf(rad, w8b[kt][2], fmaf(ea, w9b[kt][2], yb[2]+zb[2])));
          float s7 = siluf(fmaf(rad, w8b[kt][3], fmaf(ea, w9b[kt][3], yb[3]+zb[3])));
          uint4v hU, lU;
          hU[0] = pack_hi(s0,s1); hU[1] = pack_hi(s2,s3);
          hU[2] = pack_hi(s4,s5); hU[3] = pack_hi(s6,s7);
          lU[0] = pack_hi(trunc_res(s0),trunc_res(s1)); lU[1] = pack_hi(trunc_res(s2),trunc_res(s3));
          lU[2] = pack_hi(trunc_res(s4),trunc_res(s5)); lU[3] = pack_hi(trunc_res(s6),trunc_res(s7));
          m1h[kt] = __builtin_bit_cast(short8v, hU);
          m1l[kt] = __builtin_bit_cast(short8v, lU);
        }
        f32x4 acc2[4];
        #pragma unroll
        for (int nt = 0; nt < 4; nt++)
          acc2[nt] = *(const f32x4*)(SCALf + nt*16 + q*4);
        #pragma unroll
        for (int kt = 0; kt < 2; kt++)
          #pragma unroll
          for (int nt = 0; nt < 4; nt++){
            short8v w2l = *(const short8v*)(WL2 + (nt*16+c)*72 + kt*32 + q*8);
            acc2[nt] = MFMA16(W2h[kt][nt], m1h[kt], acc2[nt]);
            acc2[nt] = MFMA16(w2l,         m1h[kt], acc2[nt]);
            acc2[nt] = MFMA16(W2h[kt][nt], m1l[kt], acc2[nt]);
          }
        float m2[4][4]; float gp = 0.f;
        #pragma unroll
        for (int nt = 0; nt < 4; nt++){
          const f32x4 waq = *(const f32x4*)(SCALf+128 + nt*16 + q*4);
          #pragma unroll
          for (int r = 0; r < 4; r++){
            float mv = siluf(acc2[nt][r]); m2[nt][r] = mv;
            gp = fmaf(mv, waq[r], gp);
          }
        }
        const float gate = sigf(xorsum_q(gp) + bav);
        #pragma unroll
        for (int nt = 0; nt < 4; nt++)
          #pragma unroll
          for (int r = 0; r < 4; r++) m2[nt][r] *= gate;
        // non-atomic message write (RNE bf16)
        #pragma unroll
        for (int nt = 0; nt < 4; nt++){
          uint2v mp;
          mp.x = rne_pack(m2[nt][0], m2[nt][1]);
          mp.y = rne_pack(m2[nt][2], m2[nt][3]);
          *(uint2v*)(Mb + sl*72 + nt*16 + q*4) = mp;
        }
        short8v mgh[2], mgl[2];
        #pragma unroll
        for (int kt = 0; kt < 2; kt++){
          uint4v hU, lU;
          hU[0] = pack_hi(m2[2*kt][0],   m2[2*kt][1]);
          hU[1] = pack_hi(m2[2*kt][2],   m2[2*kt][3]);
          hU[2] = pack_hi(m2[2*kt+1][0], m2[2*kt+1][1]);
          hU[3] = pack_hi(m2[2*kt+1][2], m2[2*kt+1][3]);
          lU[0] = pack_hi(trunc_res(m2[2*kt][0]),   trunc_res(m2[2*kt][1]));
          lU[1] = pack_hi(trunc_res(m2[2*kt][2]),   trunc_res(m2[2*kt][3]));
          lU[2] = pack_hi(trunc_res(m2[2*kt+1][0]), trunc_res(m2[2*kt+1][1]));
          lU[3] = pack_hi(trunc_res(m2[2*kt+1][2]), trunc_res(m2[2*kt+1][3]));
          mgh[kt] = __builtin_bit_cast(short8v, hU);
          mgl[kt] = __builtin_bit_cast(short8v, lU);
        }
        f32x4 acc3[4];
        #pragma unroll
        for (int nt = 0; nt < 4; nt++)
          acc3[nt] = *(const f32x4*)(SCALf+64 + nt*16 + q*4);
        #pragma unroll
        for (int kt = 0; kt < 2; kt++)
          #pragma unroll
          for (int nt = 0; nt < 4; nt++){
            short8v c1 = *(const short8v*)(WC1H + (nt*16+c)*72 + kt*32 + q*8);
            acc3[nt] = MFMA16(c1, mgh[kt], acc3[nt]);
            acc3[nt] = MFMA16(c1, mgl[kt], acc3[nt]);
          }
        float pp = 0.f;
        #pragma unroll
        for (int nt = 0; nt < 4; nt++){
          const f32x4 wcq = *(const f32x4*)(SCALf+192 + nt*16 + q*4);
          #pragma unroll
          for (int r = 0; r < 4; r++)
            pp = fmaf(siluf(acc3[nt][r]), wcq[r], pp);
        }
        const float th = tanhff(xorsum_q(pp));
        if (q == 0){
          float* tdp = (float*)(Mb + sl*72 + 64);
          tdp[0] = d0*th; tdp[1] = d1*th; tdp[2] = d2*th;
        }
      }
      __syncthreads();   // M (messages + td) visible
      // register gather (slots s = n + 22j in [ch*128, ch*128+128))
      {
        const int B0 = ch*128;
        if (hasA){
          int jlo = (B0 - nA + 21) / 22;
          int jhi = (B0 + 127 - nA) / 22; if (jhi > 20) jhi = 20;
          for (int j = jlo; j <= jhi; j++){
            const uint2v u = *(const uint2v*)(Mb + (nA + 22*j - B0)*72 + fqA*4);
            gA[0] += __uint_as_float(u.x << 16);
            gA[1] += __uint_as_float(u.x & 0xFFFF0000u);
            gA[2] += __uint_as_float(u.y << 16);
            gA[3] += __uint_as_float(u.y & 0xFFFF0000u);
          }
        }
        if (hasTD){
          int jlo = (B0 - tdn + 21) / 22;
          int jhi = (B0 + 127 - tdn) / 22; if (jhi > 20) jhi = 20;
          for (int j = jlo; j <= jhi; j++)
            tdacc += ((const float*)(Mb + (tdn + 22*j - B0)*72 + 64))[tdk];
        }
      }
      __syncthreads();   // safe to overwrite M next chunk
    }
    // commit aggregation (non-atomic, disjoint addresses; SAF aliases WL2 --
    // all GEMM2 reads of WL2 finished before the last chunk's gather barrier)
    if (hasA) *(f32x4*)(SAF + nA*68 + fqA*4) = gA;
    if (hasTD) sdx4[tdn*4 + tdk] = tdacc;
    __syncthreads();  // b2

    // ---------- phase C: coord update + node MLP stage 1 (wave = (Mt, nb)) ----------
    if (tid < 88) sxc4[tid] += sdx4[tid];
    {
      short8v An1h[4], An1l[4];
      #pragma unroll
      for (int kt = 0; kt < 4; kt++){
        const short* p = wbt + WN1T_OFF + (l*64 + nb*16 + c)*128 + kt*32 + q*8;
        An1h[kt] = *(const short8v*)p;
        An1l[kt] = *(const short8v*)(p + WTOT);
      }
      float bn1v[4];
      #pragma unroll
      for (int r = 0; r < 4; r++) bn1v[r] = bn1[l*64 + nb*16 + q*4 + r];
      {
        const int node = Mt*16 + c;
        const int nodeR = node < PB ? node : PB-1;
        f32x4 acc; acc[0]=bn1v[0]; acc[1]=bn1v[1]; acc[2]=bn1v[2]; acc[3]=bn1v[3];
        #pragma unroll
        for (int kt = 0; kt < 2; kt++){
          short8v bh = *(const short8v*)(SHBH + nodeR*72 + kt*32 + q*8);
          short8v bl = *(const short8v*)(SHBL + nodeR*72 + kt*32 + q*8);
          acc = MFMA16(An1h[kt], bh, acc);
          acc = MFMA16(An1l[kt], bh, acc);
          acc = MFMA16(An1h[kt], bl, acc);
        }
        #pragma unroll
        for (int kt = 2; kt < 4; kt++){
          const f32x4 fa = *(const f32x4*)(SAF + nodeR*68 + (kt-2)*32 + q*8);
          const f32x4 fb = *(const f32x4*)(SAF + nodeR*68 + (kt-2)*32 + q*8 + 4);
          uint4v hU, lU;
          hU[0] = pack_hi(fa[0],fa[1]); hU[1] = pack_hi(fa[2],fa[3]);
          hU[2] = pack_hi(fb[0],fb[1]); hU[3] = pack_hi(fb[2],fb[3]);
          lU[0] = pack_hi(trunc_res(fa[0]),trunc_res(fa[1])); lU[1] = pack_hi(trunc_res(fa[2]),trunc_res(fa[3]));
          lU[2] = pack_hi(trunc_res(fb[0]),trunc_res(fb[1])); lU[3] = pack_hi(trunc_res(fb[2]),trunc_res(fb[3]));
          short8v bh = __builtin_bit_cast(short8v, hU);
          short8v bl = __builtin_bit_cast(short8v, lU);
          acc = MFMA16(An1h[kt], bh, acc);
          acc = MFMA16(An1l[kt], bh, acc);
          acc = MFMA16(An1h[kt], bl, acc);
        }
        if (node < PB){
          float s0 = siluf(acc[0]), s1 = siluf(acc[1]), s2 = siluf(acc[2]), s3 = siluf(acc[3]);
          uint2v hu, lu;
          hu.x = pack_hi(s0,s1); hu.y = pack_hi(s2,s3);
          lu.x = pack_hi(trunc_res(s0),trunc_res(s1)); lu.y = pack_hi(trunc_res(s2),trunc_res(s3));
          *(uint2v*)(UHI + node*72 + nb*16 + q*4) = hu;
          *(uint2v*)(ULO + node*72 + nb*16 + q*4) = lu;
        }
      }
    }
    __syncthreads();  // b3

    // ---------- phase D: node MLP stage 2 + h residual (wave = (Mt, nb)) ----------
    {
      short8v An2h[2], An2l[2];
      #pragma unroll
      for (int kt = 0; kt < 2; kt++){
        const short* p = wbt + WN2T_OFF + (l*64 + nb*16 + c)*64 + kt*32 + q*8;
        An2h[kt] = *(const short8v*)p;
        An2l[kt] = *(const short8v*)(p + WTOT);
      }
      float bn2v[4];
      #pragma unroll
      for (int r = 0; r < 4; r++) bn2v[r] = bn2[l*64 + nb*16 + q*4 + r];
      {
        const int node = Mt*16 + c;
        const int nodeR = node < PB ? node : PB-1;
        f32x4 acc; acc[0]=bn2v[0]; acc[1]=bn2v[1]; acc[2]=bn2v[2]; acc[3]=bn2v[3];
        #pragma unroll
        for (int kt = 0; kt < 2; kt++){
          short8v uh = *(const short8v*)(UHI + nodeR*72 + kt*32 + q*8);
          short8v ul = *(const short8v*)(ULO + nodeR*72 + kt*32 + q*8);
          acc = MFMA16(An2h[kt], uh, acc);
          acc = MFMA16(An2l[kt], uh, acc);
          acc = MFMA16(An2h[kt], ul, acc);
        }
        if (node < PB){
          const int idx = node*72 + nb*16 + q*4;
          uint2v hx = *(const uint2v*)(SHBH + idx);
          uint2v lx = *(const uint2v*)(SHBL + idx);
          float nh0 = __uint_as_float(hx.x << 16) + __uint_as_float(lx.x << 16) + acc[0];
          float nh1 = __uint_as_float(hx.x & 0xFFFF0000u) + __uint_as_float(lx.x & 0xFFFF0000u) + acc[1];
          float nh2 = __uint_as_float(hx.y << 16) + __uint_as_float(lx.y << 16) + acc[2];
          float nh3 = __uint_as_float(hx.y & 0xFFFF0000u) + __uint_as_float(lx.y & 0xFFFF0000u) + acc[3];
          uint2v hn, ln;
          hn.x = pack_hi(nh0,nh1); hn.y = pack_hi(nh2,nh3);
          ln.x = pack_hi(trunc_res(nh0),trunc_res(nh1)); ln.y = pack_hi(trunc_res(nh2),trunc_res(nh3));
          *(uint2v*)(SHBH + idx) = hn;
          *(uint2v*)(SHBL + idx) = ln;
        }
      }
    }
    __syncthreads();  // b4
  }

  // epilogue: smean in sdx4[88..90]
  if (tid < 3){
    float s = 0.f;
    for (int p = 0; p < PB; p++) s += sxc4[p*4+tid] - sx04[p*4+tid];
    sdx4[88+tid] = s * (1.f/PB);
  }
  __syncthreads();
  for (int i = tid; i < 66; i += 512){
    int node = i/3, k = i - node*3;
    out[b*66+i] = sxc4[node*4+k] - sx04[node*4+k] - sdx4[88+k];
  }
}

extern "C" void kernel_launch(void* const* d_in, const int* in_sizes, int n_in,
                              void* d_out, int out_size, void* d_ws, size_t ws_size,
                              hipStream_t stream){
  const float* t    = (const float*)d_in[0];
  const float* x    = (const float*)d_in[1];
  const float* h0   = (const float*)d_in[2];
  const float* embW = (const float*)d_in[3];
  const float* embB = (const float*)d_in[4];
  const float* We1  = (const float*)d_in[5];
  const float* be1  = (const float*)d_in[6];
  const float* We2  = (const float*)d_in[7];
  const float* be2  = (const float*)d_in[8];
  const float* Wa   = (const float*)d_in[9];
  const float* ba   = (const float*)d_in[10];
  const float* Wc1  = (const float*)d_in[11];
  const float* bc1  = (const float*)d_in[12];
  const float* Wc2  = (const float*)d_in[13];
  const float* Wn1  = (const float*)d_in[14];
  const float* bn1  = (const float*)d_in[15];
  const float* Wn2  = (const float*)d_in[16];
  const float* bn2  = (const float*)d_in[17];
  const int* rows   = (const int*)d_in[18];
  const int* cols   = (const int*)d_in[19];
  short* wbt = (short*)d_ws;

  hipLaunchKernelGGL(prep_weights, dim3((WTOT+255)/256), dim3(256), 0, stream,
                     We1, We2, Wc1, Wn1, Wn2, wbt);
  hipLaunchKernelGGL(egnn13, dim3(2048), dim3(512), 0, stream,
                     t, x, h0, embW, embB, We1, be1, be2, Wa, ba, bc1, Wc2,
                     bn1, bn2, rows, cols, (const short*)wbt, (float*)d_out);
}

// Round 17
// 650.330 us; speedup vs baseline: 1.3270x; 1.3270x over previous
//
#include <hip/hip_runtime.h>

#define PB 22
#define HB 64
#define EB 462
#define NL 5

// ws (shorts): hi tables then lo mirror at +WTOT
#define W1T_OFF  0        // [5][64][128]
#define W2T_OFF  40960    // [5][64][64]
#define WC1T_OFF 61440    // [5][64][64]  K sigma-permuted
#define WN1T_OFF 81920    // [5][64][128]
#define WN2T_OFF 122880   // [5][64][64]
#define WTOT     143360

typedef __attribute__((ext_vector_type(8))) short short8v;
typedef __attribute__((ext_vector_type(4))) float f32x4;
typedef __attribute__((ext_vector_type(4))) unsigned uint4v;
typedef __attribute__((ext_vector_type(2))) unsigned uint2v;

#define MFMA16(a,b,c) __builtin_amdgcn_mfma_f32_16x16x32_bf16((a),(b),(c),0,0,0)

__device__ __forceinline__ short tobf(float f){
  unsigned u = __float_as_uint(f);
  return (short)((u + 0x7FFFu + ((u>>16)&1u)) >> 16);
}
__device__ __forceinline__ float bf2f(short h){
  return __uint_as_float(((unsigned)(unsigned short)h) << 16);
}
__device__ __forceinline__ void split2(float v, short &hi, short &lo){
  hi = tobf(v);
  lo = tobf(v - bf2f(hi));
}
__device__ __forceinline__ void splitT(float v, short &hi, short &lo){
  unsigned u = __float_as_uint(v);
  hi = (short)(u >> 16);
  float lf = v - __uint_as_float(u & 0xFFFF0000u);
  lo = (short)(__float_as_uint(lf) >> 16);
}
__device__ __forceinline__ float trunc_res(float v){
  return v - __uint_as_float(__float_as_uint(v) & 0xFFFF0000u);
}
__device__ __forceinline__ unsigned pack_hi(float a, float b){
  return __builtin_amdgcn_perm(__float_as_uint(b), __float_as_uint(a), 0x07060302u);
}
// pack two f32 -> u32 of two RNE bf16 (a in low short)
__device__ __forceinline__ unsigned rne_pack(float a, float b){
  unsigned ua = __float_as_uint(a);
  unsigned ub = __float_as_uint(b);
  ua = (ua + 0x7FFFu + ((ua>>16)&1u)) >> 16;
  ub = (ub + 0x7FFFu + ((ub>>16)&1u)) & 0xFFFF0000u;
  return ua | ub;
}
__device__ __forceinline__ float siluf(float x){
  return x * __builtin_amdgcn_rcpf(1.f + __expf(-x));
}
__device__ __forceinline__ float sigf(float x){
  return __builtin_amdgcn_rcpf(1.f + __expf(-x));
}
__device__ __forceinline__ float tanhff(float x){
  return fmaf(-2.f, __builtin_amdgcn_rcpf(__expf(2.f*x) + 1.f), 1.f);
}
__device__ __forceinline__ float xorsum_q(float x){
  x += __shfl_xor(x, 16);
  x += __shfl_xor(x, 32);
  return x;
}

__global__ void prep_weights(const float* __restrict__ We1, const float* __restrict__ We2,
                             const float* __restrict__ Wc1, const float* __restrict__ Wn1,
                             const float* __restrict__ Wn2, short* __restrict__ ws){
  int i = blockIdx.x*256 + threadIdx.x;
  if (i >= WTOT) return;
  float v;
  if (i < W2T_OFF){            int l=i>>13, r=i&8191, n=r>>7, k=r&127; v = We1[(l*130+k)*64+n]; }
  else if (i < WC1T_OFF){ int j=i-W2T_OFF;  int l=j>>12, r=j&4095, n=r>>6, k=r&63; v = We2[(l*64+k)*64+n]; }
  else if (i < WN1T_OFF){ int j=i-WC1T_OFF; int l=j>>12, r=j&4095, n=r>>6, k=r&63;
    int kk = (k>>5)*32 + ((k>>2)&1)*16 + ((k>>3)&3)*4 + (k&3);
    v = Wc1[(l*64+kk)*64+n]; }
  else if (i < WN2T_OFF){ int j=i-WN1T_OFF; int l=j>>13, r=j&8191, n=r>>7, k=r&127; v = Wn1[(l*128+k)*64+n]; }
  else {                  int j=i-WN2T_OFF; int l=j>>12, r=j&4095, n=r>>6, k=r&63; v = Wn2[(l*64+k)*64+n]; }
  short hi, lo;
  split2(v, hi, lo);
  ws[i] = hi; ws[WTOT+i] = lo;
}

// ---- LDS pool byte offsets (16B aligned) ----
// SAF aliases WL2 (phase-disjoint). M rows: cols 0-63 bf16 messages, 64-69 td f32.
// smean lives in sdx4[88..90] (node-22 slots, never written by gathers).
#define O_Y1   0        // float[22*68]; aliased UHI short[22*72] in C/D
#define O_Y2   5984     // float[22*68]; aliased ULO
#define O_SHBH 11968    // short[22*72]
#define O_SHBL 15136    // short[22*72]
#define O_WL2  18304    // short[64*72]  W2-lo; aliased SAF float[22*68]
#define O_WC1  27520    // short[64*72]  Wc1-hi
#define O_M    36736    // short[64*72]  chunk messages + td
#define O_SCAL 45952    // float[256]: BE2@0 BC1@64 WA@128 WC2@192
#define O_SXC  46976    // float[23*4]
#define O_SX0  47344
#define O_SDX  47712    // float[92]; [88..90] = smean (epilogue only)
#define O_SER  48080    // uchar[512]
#define O_SEC  48592
#define POOLSZ 49104

__global__ __launch_bounds__(256, 2)
void egnn12(const float* __restrict__ gt,  const float* __restrict__ gx,
            const float* __restrict__ gh0, const float* __restrict__ embW,
            const float* __restrict__ embB,
            const float* __restrict__ We1, const float* __restrict__ be1,
            const float* __restrict__ be2, const float* __restrict__ Wa,
            const float* __restrict__ ba,  const float* __restrict__ bc1,
            const float* __restrict__ Wc2, const float* __restrict__ bn1,
            const float* __restrict__ bn2,
            const int* __restrict__ rows,  const int* __restrict__ cols,
            const short* __restrict__ wbt, float* __restrict__ out)
{
  const int b    = blockIdx.x;
  const int tid  = threadIdx.x;
  const int lane = tid & 63;
  const int wv   = tid >> 6;
  const int c    = lane & 15;
  const int q    = lane >> 4;

  __shared__ __align__(16) char pool[POOLSZ];
  float* Y1s   = (float*)(pool + O_Y1);
  float* Y2s   = (float*)(pool + O_Y2);
  short* SHBH  = (short*)(pool + O_SHBH);
  short* SHBL  = (short*)(pool + O_SHBL);
  short* WL2   = (short*)(pool + O_WL2);
  float* SAF   = (float*)(pool + O_WL2);   // alias (see layout note)
  short* WC1H  = (short*)(pool + O_WC1);
  short* Mb    = (short*)(pool + O_M);
  float* SCALf = (float*)(pool + O_SCAL);
  float* sxc4  = (float*)(pool + O_SXC);
  float* sx04  = (float*)(pool + O_SX0);
  float* sdx4  = (float*)(pool + O_SDX);
  unsigned char* SER = (unsigned char*)(pool + O_SER);
  unsigned char* SEC = (unsigned char*)(pool + O_SEC);
  short* UHI = (short*)(pool + O_Y1);
  short* ULO = (short*)(pool + O_Y2);

  // gather task assignment (fixed per thread):
  // fq-tasks: (n = task>>4, fq = task&15); taskA = tid, taskB = tid+256 (tid<96)
  // TD-tasks 0..65: threads 96..161: (n = u/3, k = u%3)
  const int nA  = tid >> 4;
  const int fqA = tid & 15;
  const int nB  = 16 + (tid >> 4);
  const bool hasB  = (tid < 96);
  const bool hasTD = (tid >= 96 && tid < 162);
  const int tdn = (tid - 96) / 3, tdk = (tid - 96) % 3;

  const float tb = gt[b];

  for (int i = tid; i < 92; i += 256){
    int node = i >> 2, k = i & 3;
    float v = (k < 3 && node < PB) ? gx[b*66 + node*3 + k] : 0.f;
    sx04[i] = v; sxc4[i] = v;
  }
  // permuted edge order: slot k (<462) = node (k%22)'s (k/22)-th incoming edge;
  // slots 462..511 -> node 21 (their messages are never gathered: gather slots
  // n+22j <= 461). Node n's real edges live at slots n+22j, j=0..20.
  for (int k = tid; k < 512; k += 256){
    int r = 21, c2 = 21;
    if (k < EB){
      int n = k % 22, s = k / 22;
      int e;
      if (s < n) e = 2*(21*s - (s*(s-1))/2 + (n - s - 1)) + 1;
      else       e = 2*(21*n - (n*(n-1))/2 + (s - n));
      r  = rows[b*EB+e] - b*PB;
      c2 = cols[b*EB+e] - b*PB;
    }
    SER[k] = (unsigned char)r; SEC[k] = (unsigned char)c2;
  }
  for (int i = tid; i < PB*HB; i += 256){
    int n = i >> 6, j = i & 63;
    float acc = embB[j] + tb*embW[PB*HB + j];
    #pragma unroll
    for (int k = 0; k < PB; k++) acc = fmaf(gh0[n*PB+k], embW[k*HB+j], acc);
    short hi, lo; splitT(acc, hi, lo);
    SHBH[n*72+j] = hi; SHBL[n*72+j] = lo;
  }
  __syncthreads();

  #pragma unroll 1
  for (int l = 0; l < NL; l++){
    // ---------- phase A ----------
    if (tid < 92) sdx4[tid] = 0.f;
    if (tid < 64){
      SCALf[      tid] = be2[l*64+tid];
      SCALf[ 64 + tid] = bc1[l*64+tid];
      SCALf[128 + tid] = Wa [l*64+tid];
      SCALf[192 + tid] = Wc2[l*64+tid];
    }
    { const short* g2lo = wbt + WTOT + W2T_OFF + l*4096;
      const short* g1hi = wbt + WC1T_OFF + l*4096;
      for (int i = tid; i < 512; i += 256){
        int col = i>>3, kc = i&7;
        *(short8v*)(WL2  + col*72 + kc*8) = *(const short8v*)(g2lo + col*64 + kc*8);
        *(short8v*)(WC1H + col*72 + kc*8) = *(const short8v*)(g1hi + col*64 + kc*8);
      } }
    // node GEMM Y1/Y2 (16 tasks over 4 waves)
    #pragma unroll 1
    for (int task = wv; task < 16; task += 4){
      const int Yv = task>>3, Mt = (task>>2)&1, nt = task&3;
      const int arow = Mt*16 + c, arowR = arow < PB ? arow : PB-1;
      const short* bp = wbt + W1T_OFF + (l*64 + nt*16 + c)*128 + Yv*64;
      const float initv = Yv ? 0.f : be1[l*64 + nt*16 + c];
      f32x4 acc = {initv, initv, initv, initv};
      #pragma unroll
      for (int kt = 0; kt < 2; kt++){
        short8v ah = *(const short8v*)(SHBH + arowR*72 + kt*32 + q*8);
        short8v al = *(const short8v*)(SHBL + arowR*72 + kt*32 + q*8);
        short8v bh = *(const short8v*)(bp + kt*32 + q*8);
        short8v bl = *(const short8v*)(bp + WTOT + kt*32 + q*8);
        acc = MFMA16(ah, bh, acc);
        acc = MFMA16(al, bh, acc);
        acc = MFMA16(ah, bl, acc);
      }
      float* Yp = Yv ? Y2s : Y1s;
      #pragma unroll
      for (int r = 0; r < 4; r++){
        int row = Mt*16 + q*4 + r;
        if (row < PB) Yp[row*68 + nt*16 + c] = acc[r];
      }
    }
    short8v W2h[2][4];
    #pragma unroll
    for (int nt = 0; nt < 4; nt++)
      #pragma unroll
      for (int kt = 0; kt < 2; kt++)
        W2h[kt][nt] = *(const short8v*)(wbt + W2T_OFF + (l*64+nt*16+c)*64 + kt*32 + q*8);
    f32x4 w8a[2], w8b[2], w9a[2], w9b[2];
    #pragma unroll
    for (int kt = 0; kt < 2; kt++){
      const float* p8 = We1 + (l*130+128)*64 + kt*32 + q*8;
      w8a[kt] = *(const f32x4*)p8;        w8b[kt] = *(const f32x4*)(p8+4);
      w9a[kt] = *(const f32x4*)(p8+64);   w9b[kt] = *(const f32x4*)(p8+68);
    }
    const float bav = ba[l];
    __syncthreads();   // b1

    // ---------- phase B: 8 chunks x 4 tiles; non-atomic M + register gather ----------
    f32x4 gA = {0.f,0.f,0.f,0.f}, gB = {0.f,0.f,0.f,0.f};
    float tdacc = 0.f;
    #pragma unroll 1
    for (int ch = 0; ch < 8; ch++){
      {
        const int e = (ch*4 + wv)*16 + c;
        const int sl = wv*16 + c;             // local slot in chunk buffer
        const int nr = SER[e], nc = SEC[e];
        const f32x4 xr = *(const f32x4*)(sxc4 + nr*4);
        const f32x4 xn = *(const f32x4*)(sxc4 + nc*4);
        const float d0 = xr[0]-xn[0], d1 = xr[1]-xn[1], d2 = xr[2]-xn[2];
        const float rad = d0*d0 + d1*d1 + d2*d2;
        const f32x4 zr = *(const f32x4*)(sx04 + nr*4);
        const f32x4 zn = *(const f32x4*)(sx04 + nc*4);
        const float g0 = zr[0]-zn[0], g1 = zr[1]-zn[1], g2 = zr[2]-zn[2];
        const float ea = g0*g0 + g1*g1 + g2*g2;
        short8v m1h[2], m1l[2];
        #pragma unroll
        for (int kt = 0; kt < 2; kt++){
          const f32x4 ya = *(const f32x4*)(Y1s + nr*68 + kt*32 + q*8);
          const f32x4 yb = *(const f32x4*)(Y1s + nr*68 + kt*32 + q*8 + 4);
          const f32x4 za = *(const f32x4*)(Y2s + nc*68 + kt*32 + q*8);
          const f32x4 zb = *(const f32x4*)(Y2s + nc*68 + kt*32 + q*8 + 4);
          float s0 = siluf(fmaf(rad, w8a[kt][0], fmaf(ea, w9a[kt][0], ya[0]+za[0])));
          float s1 = siluf(fmaf(rad, w8a[kt][1], fmaf(ea, w9a[kt][1], ya[1]+za[1])));
          float s2 = siluf(fmaf(rad, w8a[kt][2], fmaf(ea, w9a[kt][2], ya[2]+za[2])));
          float s3 = siluf(fmaf(rad, w8a[kt][3], fmaf(ea, w9a[kt][3], ya[3]+za[3])));
          float s4 = siluf(fmaf(rad, w8b[kt][0], fmaf(ea, w9b[kt][0], yb[0]+zb[0])));
          float s5 = siluf(fmaf(rad, w8b[kt][1], fmaf(ea, w9b[kt][1], yb[1]+zb[1])));
          float s6 = siluf(fmaf(rad, w8b[kt][2], fmaf(ea, w9b[kt][2], yb[2]+zb[2])));
          float s7 = siluf(fmaf(rad, w8b[kt][3], fmaf(ea, w9b[kt][3], yb[3]+zb[3])));
          uint4v hU, lU;
          hU[0] = pack_hi(s0,s1); hU[1] = pack_hi(s2,s3);
          hU[2] = pack_hi(s4,s5); hU[3] = pack_hi(s6,s7);
          lU[0] = pack_hi(trunc_res(s0),trunc_res(s1)); lU[1] = pack_hi(trunc_res(s2),trunc_res(s3));
          lU[2] = pack_hi(trunc_res(s4),trunc_res(s5)); lU[3] = pack_hi(trunc_res(s6),trunc_res(s7));
          m1h[kt] = __builtin_bit_cast(short8v, hU);
          m1l[kt] = __builtin_bit_cast(short8v, lU);
        }
        f32x4 acc2[4];
        #pragma unroll
        for (int nt = 0; nt < 4; nt++)
          acc2[nt] = *(const f32x4*)(SCALf + nt*16 + q*4);
        #pragma unroll
        for (int kt = 0; kt < 2; kt++)
          #pragma unroll
          for (int nt = 0; nt < 4; nt++){
            short8v w2l = *(const short8v*)(WL2 + (nt*16+c)*72 + kt*32 + q*8);
            acc2[nt] = MFMA16(W2h[kt][nt], m1h[kt], acc2[nt]);
            acc2[nt] = MFMA16(w2l,         m1h[kt], acc2[nt]);
            acc2[nt] = MFMA16(W2h[kt][nt], m1l[kt], acc2[nt]);
          }
        float m2[4][4]; float gp = 0.f;
        #pragma unroll
        for (int nt = 0; nt < 4; nt++){
          const f32x4 waq = *(const f32x4*)(SCALf+128 + nt*16 + q*4);
          #pragma unroll
          for (int r = 0; r < 4; r++){
            float mv = siluf(acc2[nt][r]); m2[nt][r] = mv;
            gp = fmaf(mv, waq[r], gp);
          }
        }
        const float gate = sigf(xorsum_q(gp) + bav);
        #pragma unroll
        for (int nt = 0; nt < 4; nt++)
          #pragma unroll
          for (int r = 0; r < 4; r++) m2[nt][r] *= gate;
        // non-atomic message write (RNE bf16)
        #pragma unroll
        for (int nt = 0; nt < 4; nt++){
          uint2v mp;
          mp.x = rne_pack(m2[nt][0], m2[nt][1]);
          mp.y = rne_pack(m2[nt][2], m2[nt][3]);
          *(uint2v*)(Mb + sl*72 + nt*16 + q*4) = mp;
        }
        short8v mgh[2], mgl[2];
        #pragma unroll
        for (int kt = 0; kt < 2; kt++){
          uint4v hU, lU;
          hU[0] = pack_hi(m2[2*kt][0],   m2[2*kt][1]);
          hU[1] = pack_hi(m2[2*kt][2],   m2[2*kt][3]);
          hU[2] = pack_hi(m2[2*kt+1][0], m2[2*kt+1][1]);
          hU[3] = pack_hi(m2[2*kt+1][2], m2[2*kt+1][3]);
          lU[0] = pack_hi(trunc_res(m2[2*kt][0]),   trunc_res(m2[2*kt][1]));
          lU[1] = pack_hi(trunc_res(m2[2*kt][2]),   trunc_res(m2[2*kt][3]));
          lU[2] = pack_hi(trunc_res(m2[2*kt+1][0]), trunc_res(m2[2*kt+1][1]));
          lU[3] = pack_hi(trunc_res(m2[2*kt+1][2]), trunc_res(m2[2*kt+1][3]));
          mgh[kt] = __builtin_bit_cast(short8v, hU);
          mgl[kt] = __builtin_bit_cast(short8v, lU);
        }
        f32x4 acc3[4];
        #pragma unroll
        for (int nt = 0; nt < 4; nt++)
          acc3[nt] = *(const f32x4*)(SCALf+64 + nt*16 + q*4);
        #pragma unroll
        for (int kt = 0; kt < 2; kt++)
          #pragma unroll
          for (int nt = 0; nt < 4; nt++){
            short8v c1 = *(const short8v*)(WC1H + (nt*16+c)*72 + kt*32 + q*8);
            acc3[nt] = MFMA16(c1, mgh[kt], acc3[nt]);
            acc3[nt] = MFMA16(c1, mgl[kt], acc3[nt]);
          }
        float pp = 0.f;
        #pragma unroll
        for (int nt = 0; nt < 4; nt++){
          const f32x4 wcq = *(const f32x4*)(SCALf+192 + nt*16 + q*4);
          #pragma unroll
          for (int r = 0; r < 4; r++)
            pp = fmaf(siluf(acc3[nt][r]), wcq[r], pp);
        }
        const float th = tanhff(xorsum_q(pp));
        if (q == 0){
          float* tdp = (float*)(Mb + sl*72 + 64);
          tdp[0] = d0*th; tdp[1] = d1*th; tdp[2] = d2*th;
        }
      }
      __syncthreads();   // M (messages + td) visible
      // register gather for this chunk (slots s = n + 22j in [ch*64, ch*64+64))
      {
        const int B0 = ch*64;
        {
          int jlo = (B0 - nA + 21) / 22;
          int jhi = (B0 + 63 - nA) / 22; if (jhi > 20) jhi = 20;
          for (int j = jlo; j <= jhi; j++){
            const uint2v u = *(const uint2v*)(Mb + (nA + 22*j - B0)*72 + fqA*4);
            gA[0] += __uint_as_float(u.x << 16);
            gA[1] += __uint_as_float(u.x & 0xFFFF0000u);
            gA[2] += __uint_as_float(u.y << 16);
            gA[3] += __uint_as_float(u.y & 0xFFFF0000u);
          }
        }
        if (hasB){
          int jlo = (B0 - nB + 21) / 22;
          int jhi = (B0 + 63 - nB) / 22; if (jhi > 20) jhi = 20;
          for (int j = jlo; j <= jhi; j++){
            const uint2v u = *(const uint2v*)(Mb + (nB + 22*j - B0)*72 + fqA*4);
            gB[0] += __uint_as_float(u.x << 16);
            gB[1] += __uint_as_float(u.x & 0xFFFF0000u);
            gB[2] += __uint_as_float(u.y << 16);
            gB[3] += __uint_as_float(u.y & 0xFFFF0000u);
          }
        }
        if (hasTD){
          int jlo = (B0 - tdn + 21) / 22;
          int jhi = (B0 + 63 - tdn) / 22; if (jhi > 20) jhi = 20;
          for (int j = jlo; j <= jhi; j++)
            tdacc += ((const float*)(Mb + (tdn + 22*j - B0)*72 + 64))[tdk];
        }
      }
      __syncthreads();   // safe to overwrite M next chunk
    }
    // commit aggregation (non-atomic, disjoint addresses; SAF aliases WL2 --
    // all GEMM2 reads of WL2 finished before the last chunk's gather barrier)
    *(f32x4*)(SAF + nA*68 + fqA*4) = gA;
    if (hasB) *(f32x4*)(SAF + nB*68 + fqA*4) = gB;
    if (hasTD) sdx4[tdn*4 + tdk] = tdacc;
    __syncthreads();  // b2

    // ---------- phase C: coord update + node MLP stage 1 ----------
    if (tid < 88) sxc4[tid] += sdx4[tid];
    {
      short8v An1h[4], An1l[4];
      #pragma unroll
      for (int kt = 0; kt < 4; kt++){
        const short* p = wbt + WN1T_OFF + (l*64 + wv*16 + c)*128 + kt*32 + q*8;
        An1h[kt] = *(const short8v*)p;
        An1l[kt] = *(const short8v*)(p + WTOT);
      }
      float bn1v[4];
      #pragma unroll
      for (int r = 0; r < 4; r++) bn1v[r] = bn1[l*64 + wv*16 + q*4 + r];
      #pragma unroll 1
      for (int tt = 0; tt < 2; tt++){
        const int node = tt*16 + c;
        const int nodeR = node < PB ? node : PB-1;
        f32x4 acc; acc[0]=bn1v[0]; acc[1]=bn1v[1]; acc[2]=bn1v[2]; acc[3]=bn1v[3];
        #pragma unroll
        for (int kt = 0; kt < 2; kt++){
          short8v bh = *(const short8v*)(SHBH + nodeR*72 + kt*32 + q*8);
          short8v bl = *(const short8v*)(SHBL + nodeR*72 + kt*32 + q*8);
          acc = MFMA16(An1h[kt], bh, acc);
          acc = MFMA16(An1l[kt], bh, acc);
          acc = MFMA16(An1h[kt], bl, acc);
        }
        #pragma unroll
        for (int kt = 2; kt < 4; kt++){
          const f32x4 fa = *(const f32x4*)(SAF + nodeR*68 + (kt-2)*32 + q*8);
          const f32x4 fb = *(const f32x4*)(SAF + nodeR*68 + (kt-2)*32 + q*8 + 4);
          uint4v hU, lU;
          hU[0] = pack_hi(fa[0],fa[1]); hU[1] = pack_hi(fa[2],fa[3]);
          hU[2] = pack_hi(fb[0],fb[1]); hU[3] = pack_hi(fb[2],fb[3]);
          lU[0] = pack_hi(trunc_res(fa[0]),trunc_res(fa[1])); lU[1] = pack_hi(trunc_res(fa[2]),trunc_res(fa[3]));
          lU[2] = pack_hi(trunc_res(fb[0]),trunc_res(fb[1])); lU[3] = pack_hi(trunc_res(fb[2]),trunc_res(fb[3]));
          short8v bh = __builtin_bit_cast(short8v, hU);
          short8v bl = __builtin_bit_cast(short8v, lU);
          acc = MFMA16(An1h[kt], bh, acc);
          acc = MFMA16(An1l[kt], bh, acc);
          acc = MFMA16(An1h[kt], bl, acc);
        }
        if (node < PB){
          float s0 = siluf(acc[0]), s1 = siluf(acc[1]), s2 = siluf(acc[2]), s3 = siluf(acc[3]);
          uint2v hu, lu;
          hu.x = pack_hi(s0,s1); hu.y = pack_hi(s2,s3);
          lu.x = pack_hi(trunc_res(s0),trunc_res(s1)); lu.y = pack_hi(trunc_res(s2),trunc_res(s3));
          *(uint2v*)(UHI + node*72 + wv*16 + q*4) = hu;
          *(uint2v*)(ULO + node*72 + wv*16 + q*4) = lu;
        }
      }
    }
    __syncthreads();  // b3

    // ---------- phase D: node MLP stage 2 + h residual ----------
    {
      short8v An2h[2], An2l[2];
      #pragma unroll
      for (int kt = 0; kt < 2; kt++){
        const short* p = wbt + WN2T_OFF + (l*64 + wv*16 + c)*64 + kt*32 + q*8;
        An2h[kt] = *(const short8v*)p;
        An2l[kt] = *(const short8v*)(p + WTOT);
      }
      float bn2v[4];
      #pragma unroll
      for (int r = 0; r < 4; r++) bn2v[r] = bn2[l*64 + wv*16 + q*4 + r];
      #pragma unroll 1
      for (int tt = 0; tt < 2; tt++){
        const int node = tt*16 + c;
        const int nodeR = node < PB ? node : PB-1;
        f32x4 acc; acc[0]=bn2v[0]; acc[1]=bn2v[1]; acc[2]=bn2v[2]; acc[3]=bn2v[3];
        #pragma unroll
        for (int kt = 0; kt < 2; kt++){
          short8v uh = *(const short8v*)(UHI + nodeR*72 + kt*32 + q*8);
          short8v ul = *(const short8v*)(ULO + nodeR*72 + kt*32 + q*8);
          acc = MFMA16(An2h[kt], uh, acc);
          acc = MFMA16(An2l[kt], uh, acc);
          acc = MFMA16(An2h[kt], ul, acc);
        }
        if (node < PB){
          const int idx = node*72 + wv*16 + q*4;
          uint2v hx = *(const uint2v*)(SHBH + idx);
          uint2v lx = *(const uint2v*)(SHBL + idx);
          float nh0 = __uint_as_float(hx.x << 16) + __uint_as_float(lx.x << 16) + acc[0];
          float nh1 = __uint_as_float(hx.x & 0xFFFF0000u) + __uint_as_float(lx.x & 0xFFFF0000u) + acc[1];
          float nh2 = __uint_as_float(hx.y << 16) + __uint_as_float(lx.y << 16) + acc[2];
          float nh3 = __uint_as_float(hx.y & 0xFFFF0000u) + __uint_as_float(lx.y & 0xFFFF0000u) + acc[3];
          uint2v hn, ln;
          hn.x = pack_hi(nh0,nh1); hn.y = pack_hi(nh2,nh3);
          ln.x = pack_hi(trunc_res(nh0),trunc_res(nh1)); ln.y = pack_hi(trunc_res(nh2),trunc_res(nh3));
          *(uint2v*)(SHBH + idx) = hn;
          *(uint2v*)(SHBL + idx) = ln;
        }
      }
    }
    __syncthreads();  // b4
  }

  // epilogue: smean in sdx4[88..90] (node-22 slots, unused by gathers)
  if (tid < 3){
    float s = 0.f;
    for (int p = 0; p < PB; p++) s += sxc4[p*4+tid] - sx04[p*4+tid];
    sdx4[88+tid] = s * (1.f/PB);
  }
  __syncthreads();
  for (int i = tid; i < 66; i += 256){
    int node = i/3, k = i - node*3;
    out[b*66+i] = sxc4[node*4+k] - sx04[node*4+k] - sdx4[88+k];
  }
}

extern "C" void kernel_launch(void* const* d_in, const int* in_sizes, int n_in,
                              void* d_out, int out_size, void* d_ws, size_t ws_size,
                              hipStream_t stream){
  const float* t    = (const float*)d_in[0];
  const float* x    = (const float*)d_in[1];
  const float* h0   = (const float*)d_in[2];
  const float* embW = (const float*)d_in[3];
  const float* embB = (const float*)d_in[4];
  const float* We1  = (const float*)d_in[5];
  const float* be1  = (const float*)d_in[6];
  const float* We2  = (const float*)d_in[7];
  const float* be2  = (const float*)d_in[8];
  const float* Wa   = (const float*)d_in[9];
  const float* ba   = (const float*)d_in[10];
  const float* Wc1  = (const float*)d_in[11];
  const float* bc1  = (const float*)d_in[12];
  const float* Wc2  = (const float*)d_in[13];
  const float* Wn1  = (const float*)d_in[14];
  const float* bn1  = (const float*)d_in[15];
  const float* Wn2  = (const float*)d_in[16];
  const float* bn2  = (const float*)d_in[17];
  const int* rows   = (const int*)d_in[18];
  const int* cols   = (const int*)d_in[19];
  short* wbt = (short*)d_ws;

  hipLaunchKernelGGL(prep_weights, dim3((WTOT+255)/256), dim3(256), 0, stream,
                     We1, We2, Wc1, Wn1, Wn2, wbt);
  hipLaunchKernelGGL(egnn12, dim3(2048), dim3(256), 0, stream,
                     t, x, h0, embW, embB, We1, be1, be2, Wa, ba, bc1, Wc2,
                     bn1, bn2, rows, cols, (const short*)wbt, (float*)d_out);
}